// Round 5
// baseline (284.623 us; speedup 1.0000x reference)
//
#include <hip/hip_runtime.h>

// Problem: B=2, H=4, S=4096, D=64.  q,k,v fp32; mask int32.
// Outputs (fp32, concatenated): out [2,4,4096,64] then attn [2,4,4096,4096].
#define SDIM 4096
#define DDIM 64
#define HDIM 4
#define OUTN (2 * HDIM * SDIM * DDIM)   // 2,097,152 floats of `out` before `attn`

typedef short short8 __attribute__((ext_vector_type(8)));  // 8 x bf16 (4 VGPRs)
typedef short bh4    __attribute__((ext_vector_type(4)));  // 4 x bf16 (2 VGPRs)
typedef float f32x4  __attribute__((ext_vector_type(4)));

__device__ inline short f2bf(float f) {
    // round-to-nearest-even fp32 -> bf16
    unsigned u = __builtin_bit_cast(unsigned, f);
    u = (u + 0x7fffu + ((u >> 16) & 1u)) >> 16;
    return (short)u;
}
__device__ inline float bf2f(short s) {
    unsigned u = ((unsigned)(unsigned short)s) << 16;
    return __builtin_bit_cast(float, u);
}

// LDS tiles are [64][64] shorts (128 B rows), XOR-swizzled: the 16-B chunk
// index (byte bits 4-6) is XORed with (row&7).  Keeps ds_read_b128 at the
// 8-cycle minimum (8 lanes / 4-bank group) with zero padding.
__device__ inline short* ldsp(short* base, int row, int colshort) {
    int byte = (row << 7) + (colshort << 1);
    byte ^= (row & 7) << 4;
    return (short*)((char*)base + byte);
}

// async 16-B global -> LDS DMA (linear LDS dest; source is pre-swizzled)
__device__ inline void g2l16(const short* g, short* l) {
    __builtin_amdgcn_global_load_lds(
        (const __attribute__((address_space(1))) unsigned int*)g,
        (__attribute__((address_space(3))) unsigned int*)l, 16, 0, 0);
}

// ---------------------------------------------------------------------------
// Pre-pass 1: bit-pack mask (1,S,S) int32 -> 1 bit/elem, TRANSPOSED layout:
// bits[tchunk * SDIM + row] covers (row, t in [tchunk*64, tchunk*64+64)).
// (Transposed so the fused kernel's 16-row mask fetch is coalesced.)
__global__ void pack_mask(const int* __restrict__ mask,
                          unsigned long long* __restrict__ bits) {
    int gid = blockIdx.x * 256 + threadIdx.x;
    int v = (mask[gid] != 0);
    unsigned long long bal = __ballot(v);
    if ((threadIdx.x & 63) == 0) {
        int row = gid >> 12;                 // 4096 t per row
        int tch = (gid & (SDIM - 1)) >> 6;
        bits[(size_t)tch * SDIM + row] = bal;
    }
}

// ---------------------------------------------------------------------------
// Pre-pass 2: fp32 -> bf16 copy (for Q and K). 8 elems/thread.
__global__ void cvt_bf16(const float* __restrict__ src, short* __restrict__ dst) {
    int gid = blockIdx.x * 256 + threadIdx.x;
    const float* p = src + (size_t)gid * 8;
    f32x4 a = *(const f32x4*)p;
    f32x4 b = *(const f32x4*)(p + 4);
    short8 o;
#pragma unroll
    for (int j = 0; j < 4; ++j) { o[j] = f2bf(a[j]); o[j + 4] = f2bf(b[j]); }
    *(short8*)(dst + (size_t)gid * 8) = o;
}

// ---------------------------------------------------------------------------
// Pre-pass 3: VT[b][h][d][t] = bf16(V[b][h][t][d])  (4 MB in ws).
__global__ void transpose_v(const float* __restrict__ v, short* __restrict__ vt) {
    int gid = blockIdx.x * 256 + threadIdx.x;          // 8*64*512 = 262144 threads
    int t8 = gid & (SDIM / 8 - 1);                     // 0..511
    int d  = (gid >> 9) & (DDIM - 1);
    int bh = gid >> 15;                                // 0..7
    short8 o;
#pragma unroll
    for (int j = 0; j < 8; ++j)
        o[j] = f2bf(v[((size_t)bh * SDIM + t8 * 8 + j) * DDIM + d]);
    *(short8*)(vt + ((size_t)bh * DDIM + d) * SDIM + t8 * 8) = o;
}

// ---------------------------------------------------------------------------
// Fused kernel: block = (head h, 64 q-rows, BOTH batches, half the t range).
// OPERAND-SWAPPED QK^T: S^T = K Q^T, so lane (l,qd) holds S[m=l][t=16nt+4qd+rg]
// -- 4 consecutive t per f32x4.  Enables:
//   * attn stored DIRECT from registers in fp32 (dense 64-B segments, no LDS)
//   * Ps writes as 4x ds_write_b64 (bf16) for the PV A-frag only
//   * 1 mask u64 load per lane per tile (transposed bit array)
// PV: O_b += P_b V_b (MFMA), P1 = 1-P0 recomputed in-register.
// Partial O: tz=0 -> out, tz=1 -> ws; `combine` sums.
__global__ __launch_bounds__(256, 2)
void attn_fused(const short* __restrict__ qg, const short* __restrict__ kg,
                const short* __restrict__ vtg,
                const unsigned long long* __restrict__ mbits,
                float* __restrict__ attng, float* __restrict__ outg,
                float* __restrict__ opart) {
    __shared__ short Ks [2][64 * 64];       // K tile, rows = t (swizzled)
    __shared__ short VTs[2][64 * 64];       // V^T tile, rows = d (swizzled)
    __shared__ short Ps [64 * 64];          // P0 tile, rows = m (swizzled)

    const int h   = blockIdx.y;
    const int s0  = blockIdx.x << 6;
    const int tz  = blockIdx.z;             // t-half: [tz*2048, tz*2048+2048)
    const int tid = threadIdx.x;
    const int wv  = tid >> 6;               // wave 0..3, owns q-rows 16*wv..+15
    const int ln  = tid & 63;
    const int l   = ln & 15;
    const int qd  = ln >> 4;                // quad

    // Q B-fragments (same register layout as A: [m=lane&15][k=quad*8+j]).
    short8 qf[2][2];
#pragma unroll
    for (int b = 0; b < 2; ++b) {
        const size_t rb = ((size_t)(b * HDIM + h) * SDIM + (s0 + wv * 16 + l)) * DDIM;
#pragma unroll
        for (int kc = 0; kc < 2; ++kc)
            qf[b][kc] = *(const short8*)(qg + rb + kc * 32 + qd * 8);
    }

    f32x4 oacc[2][4];
#pragma unroll
    for (int b = 0; b < 2; ++b)
#pragma unroll
        for (int nd = 0; nd < 4; ++nd)
            oacc[b][nd] = (f32x4){0.f, 0.f, 0.f, 0.f};

    // staging geometry: lane ln covers dest row (p*32 + wv*8 + ln>>3),
    // chunk (ln&7); source chunk is inverse-swizzled so swizzled reads match.
    const int ln8 = ln >> 3;                 // dest row within 8-row group
    const int sc_ = (ln & 7) ^ ln8;          // pre-swizzled source 16-B chunk
    const int mrow = s0 + wv * 16 + l;       // this lane's q-row (mask & store)

    const int tbeg = tz * (SDIM / 2);
    for (int t0 = tbeg; t0 < tbeg + SDIM / 2; t0 += 64) {
        __syncthreads();   // all waves done reading Ks/VTs of previous tile
#pragma unroll
        for (int b = 0; b < 2; ++b) {
            const short* kb = kg  + ((size_t)(b * HDIM + h) * SDIM + t0) * DDIM;
            const short* vb = vtg + ((size_t)(b * HDIM + h) * DDIM) * SDIM + t0;
#pragma unroll
            for (int p = 0; p < 2; ++p) {
                int rr = p * 32 + wv * 8 + ln8;
                g2l16(kb + (size_t)rr * DDIM + sc_ * 8, &Ks [b][p * 2048 + wv * 512]);
                g2l16(vb + (size_t)rr * SDIM + sc_ * 8, &VTs[b][p * 2048 + wv * 512]);
            }
        }
        // mask bits: one u64 = this lane's q-row x the 64 t of this tile
        // (coalesced: 16 consecutive u64 per quad; issued under DMA latency)
        unsigned long long mw = mbits[(size_t)(t0 >> 6) * SDIM + mrow];
        __syncthreads();   // vmcnt(0) drain -> staged tiles visible

        // S^T = K Q^T: A-frag from Ks rows (t), B-frag = Q regs.
        // C layout: col=l -> m, row=16nt+qd*4+rg -> t.
        f32x4 sc[2][4];
#pragma unroll
        for (int b = 0; b < 2; ++b)
#pragma unroll
            for (int nt = 0; nt < 4; ++nt) {
                f32x4 acc = (f32x4){0.f, 0.f, 0.f, 0.f};
#pragma unroll
                for (int kc = 0; kc < 2; ++kc) {
                    short8 kf = *(const short8*)ldsp(&Ks[b][0], nt * 16 + l, kc * 32 + qd * 8);
                    acc = __builtin_amdgcn_mfma_f32_16x16x32_bf16(kf, qf[b][kc], acc, 0, 0, 0);
                }
                sc[b][nt] = acc;
            }

        // batch-pair sigmoid (pointwise); keep p0 in fp32 regs for the store,
        // pack bf16 -> Ps (4x ds_write_b64, wave-local rows) for the PV A-frag.
        f32x4 p0[4];
#pragma unroll
        for (int nt = 0; nt < 4; ++nt) {
#pragma unroll
            for (int rg = 0; rg < 4; ++rg) {
                float dd = (sc[0][nt][rg] - sc[1][nt][rg]) * 0.125f;
                bool msk = (mw >> (nt * 16 + qd * 4 + rg)) & 1ull;
                p0[nt][rg] = msk ? 0.5f : __builtin_amdgcn_rcpf(1.f + __expf(-dd));
            }
            bh4 pb;
#pragma unroll
            for (int rg = 0; rg < 4; ++rg) pb[rg] = f2bf(p0[nt][rg]);
            *(bh4*)ldsp(&Ps[0], wv * 16 + l, nt * 16 + qd * 4) = pb;
        }

        // attn store DIRECT from registers: per instr 16 rows x 64 B dense.
        {
            float* d0 = attng + ((size_t)h * SDIM + mrow) * (size_t)SDIM + t0 + qd * 4;
            float* d1 = d0 + (size_t)HDIM * SDIM * SDIM;
#pragma unroll
            for (int nt = 0; nt < 4; ++nt) {
                __builtin_nontemporal_store(p0[nt], (f32x4*)(d0 + nt * 16));
                f32x4 p1;
#pragma unroll
                for (int j = 0; j < 4; ++j) p1[j] = 1.f - p0[nt][j];
                __builtin_nontemporal_store(p1, (f32x4*)(d1 + nt * 16));
            }
        }

        // PV: A from Ps (own 16-row strip; b=1 frag = 1 - b=0 frag),
        // B from VTs (rows = d)
#pragma unroll
        for (int kc = 0; kc < 2; ++kc) {
            short8 af0 = *(const short8*)ldsp(&Ps[0], wv * 16 + l, kc * 32 + qd * 8);
            short8 af1;
#pragma unroll
            for (int j = 0; j < 8; ++j) af1[j] = f2bf(1.f - bf2f(af0[j]));
#pragma unroll
            for (int nd = 0; nd < 4; ++nd) {
                short8 bf0 = *(const short8*)ldsp(&VTs[0][0], nd * 16 + l, kc * 32 + qd * 8);
                oacc[0][nd] = __builtin_amdgcn_mfma_f32_16x16x32_bf16(af0, bf0, oacc[0][nd], 0, 0, 0);
                short8 bf1 = *(const short8*)ldsp(&VTs[1][0], nd * 16 + l, kc * 32 + qd * 8);
                oacc[1][nd] = __builtin_amdgcn_mfma_f32_16x16x32_bf16(af1, bf1, oacc[1][nd], 0, 0, 0);
            }
        }
    }

    // epilogue: partial O (C-layout: col=lane&15, row=quad*4+reg).
    // tz=0 writes straight into `out`; tz=1 into the ws slice.
    float* dst = (tz == 0) ? outg : opart;
#pragma unroll
    for (int b = 0; b < 2; ++b)
#pragma unroll
        for (int nd = 0; nd < 4; ++nd)
#pragma unroll
            for (int rg = 0; rg < 4; ++rg) {
                int srow = s0 + wv * 16 + qd * 4 + rg;
                dst[((size_t)(b * HDIM + h) * SDIM + srow) * DDIM + nd * 16 + l] =
                    oacc[b][nd][rg];
            }
}

// ---------------------------------------------------------------------------
// out += the tz=1 partial slice (out already holds the tz=0 partial).
__global__ void combine(const float* __restrict__ opart, float* __restrict__ outg) {
    int gid = blockIdx.x * 256 + threadIdx.x;           // OUTN/4 threads
    f32x4 a = *(const f32x4*)(outg + (size_t)gid * 4);
    f32x4 b = *(const f32x4*)(opart + (size_t)gid * 4);
    *(f32x4*)(outg + (size_t)gid * 4) = a + b;
}

// ---------------------------------------------------------------------------
extern "C" void kernel_launch(void* const* d_in, const int* in_sizes, int n_in,
                              void* d_out, int out_size, void* d_ws, size_t ws_size,
                              hipStream_t stream) {
    (void)in_sizes; (void)n_in; (void)out_size; (void)ws_size;
    const float* qg  = (const float*)d_in[0];
    const float* kg  = (const float*)d_in[1];
    const float* vg  = (const float*)d_in[2];
    const int*   msk = (const int*)d_in[3];

    float* outg  = (float*)d_out;
    float* attng = outg + (size_t)OUTN;

    char* ws = (char*)d_ws;
    unsigned long long* bits = (unsigned long long*)ws;            // 2 MB
    short* qb = (short*)(ws + (size_t) 2 * 1024 * 1024);           // 4 MB
    short* kb = (short*)(ws + (size_t) 6 * 1024 * 1024);           // 4 MB
    short* vt = (short*)(ws + (size_t)10 * 1024 * 1024);           // 4 MB
    float* op = (float*)(ws + (size_t)14 * 1024 * 1024);           // 8.4 MB

    pack_mask  <<<dim3(SDIM * SDIM / 256), dim3(256), 0, stream>>>(msk, bits);
    cvt_bf16   <<<dim3(OUTN / (8 * 256)), dim3(256), 0, stream>>>(qg, qb);
    cvt_bf16   <<<dim3(OUTN / (8 * 256)), dim3(256), 0, stream>>>(kg, kb);
    transpose_v<<<dim3(OUTN / (8 * 256)), dim3(256), 0, stream>>>(vg, vt);
    attn_fused <<<dim3(SDIM / 64, HDIM, 2), dim3(256), 0, stream>>>(
        qb, kb, vt, bits, attng, outg, op);
    combine    <<<dim3(OUTN / (4 * 256)), dim3(256), 0, stream>>>(op, outg);
}

// Round 6
// 215.308 us; speedup vs baseline: 1.3219x; 1.3219x over previous
//
#include <hip/hip_runtime.h>

// Problem: B=2, H=4, S=4096, D=64.  q,k,v fp32; mask int32.
// Outputs (fp32, concatenated): out [2,4,4096,64] then attn [2,4,4096,4096].
#define SDIM 4096
#define DDIM 64
#define HDIM 4
#define OUTN (2 * HDIM * SDIM * DDIM)   // 2,097,152 floats of `out` before `attn`

typedef short short8 __attribute__((ext_vector_type(8)));  // 8 x bf16 (4 VGPRs)
typedef short bh4    __attribute__((ext_vector_type(4)));  // 4 x bf16 (2 VGPRs)
typedef float f32x4  __attribute__((ext_vector_type(4)));

__device__ inline short f2bf(float f) {
    // round-to-nearest-even fp32 -> bf16
    unsigned u = __builtin_bit_cast(unsigned, f);
    u = (u + 0x7fffu + ((u >> 16) & 1u)) >> 16;
    return (short)u;
}
__device__ inline float bf2f(short s) {
    unsigned u = ((unsigned)(unsigned short)s) << 16;
    return __builtin_bit_cast(float, u);
}

// LDS tiles are [64][64] shorts (128 B rows), XOR-swizzled: the 16-B chunk
// index (byte bits 4-6) is XORed with (row&7).  Keeps ds_read_b128 at the
// 8-cycle minimum (8 lanes / 4-bank group) with zero padding.
__device__ inline short* ldsp(short* base, int row, int colshort) {
    int byte = (row << 7) + (colshort << 1);
    byte ^= (row & 7) << 4;
    return (short*)((char*)base + byte);
}

// async 16-B global -> LDS DMA (linear LDS dest; source is pre-swizzled)
__device__ inline void g2l16(const short* g, short* l) {
    __builtin_amdgcn_global_load_lds(
        (const __attribute__((address_space(1))) unsigned int*)g,
        (__attribute__((address_space(3))) unsigned int*)l, 16, 0, 0);
}

// ---------------------------------------------------------------------------
// Pre-pass 1: bit-pack mask (1,S,S) int32 -> 1 bit per element (2 MB in ws).
__global__ void pack_mask(const int* __restrict__ mask,
                          unsigned long long* __restrict__ bits) {
    int gid = blockIdx.x * 256 + threadIdx.x;
    int v = (mask[gid] != 0);
    unsigned long long bal = __ballot(v);
    if ((threadIdx.x & 63) == 0) bits[gid >> 6] = bal;
}

// ---------------------------------------------------------------------------
// Pre-pass 2: fp32 -> bf16 copy (for Q and K). 8 elems/thread.
__global__ void cvt_bf16(const float* __restrict__ src, short* __restrict__ dst) {
    int gid = blockIdx.x * 256 + threadIdx.x;
    const float* p = src + (size_t)gid * 8;
    f32x4 a = *(const f32x4*)p;
    f32x4 b = *(const f32x4*)(p + 4);
    short8 o;
#pragma unroll
    for (int j = 0; j < 4; ++j) { o[j] = f2bf(a[j]); o[j + 4] = f2bf(b[j]); }
    *(short8*)(dst + (size_t)gid * 8) = o;
}

// ---------------------------------------------------------------------------
// Pre-pass 3: VT[b][h][d][t] = bf16(V[b][h][t][d])  (4 MB in ws).
__global__ void transpose_v(const float* __restrict__ v, short* __restrict__ vt) {
    int gid = blockIdx.x * 256 + threadIdx.x;          // 8*64*512 = 262144 threads
    int t8 = gid & (SDIM / 8 - 1);                     // 0..511
    int d  = (gid >> 9) & (DDIM - 1);
    int bh = gid >> 15;                                // 0..7
    short8 o;
#pragma unroll
    for (int j = 0; j < 8; ++j)
        o[j] = f2bf(v[((size_t)bh * SDIM + t8 * 8 + j) * DDIM + d]);
    *(short8*)(vt + ((size_t)bh * DDIM + d) * SDIM + t8 * 8) = o;
}

// ---------------------------------------------------------------------------
// Fused kernel: block = (head h, 64 q-rows, BOTH batches, half the t range).
// 2-PHASE PIPELINE (T3 minimal recipe): K/V tiles double-buffered; each
// iteration issues next tile's global_load_lds FIRST, computes the current
// tile, then a SINGLE __syncthreads() (vmcnt(0) drain is cheap: the DMA had
// the whole compute phase to land).  Compute per tile is byte-identical to
// the verified R3 kernel: S_b = Q_b K_b^T (MFMA) -> p0 = sigmoid((S0-S1)/8)
// (0.5 where masked) -> P to LDS (bf16, wave-local) -> DENSE coalesced fp32
// attn write (4 rows x 256 B per instr) -> O_b += P_b V_b (MFMA).
// Partial O to ws; combined by `combine`.  LDS = 80 KB -> 2 blocks/CU.
__global__ __launch_bounds__(256, 2)
void attn_fused(const short* __restrict__ qg, const short* __restrict__ kg,
                const short* __restrict__ vtg,
                const unsigned long long* __restrict__ mbits,
                float* __restrict__ attng, float* __restrict__ opart) {
    __shared__ short Ks [2][2][64 * 64];    // [buf][batch], rows = t (swizzled)
    __shared__ short VTs[2][2][64 * 64];    // [buf][batch], rows = d (swizzled)
    __shared__ short Ps [2][64 * 64];       // [batch], rows = m (swizzled)

    const int h   = blockIdx.y;
    const int s0  = blockIdx.x << 6;
    const int tz  = blockIdx.z;             // t-half: [tz*2048, tz*2048+2048)
    const int tid = threadIdx.x;
    const int wv  = tid >> 6;               // wave 0..3, owns q-rows 16*wv..+15
    const int ln  = tid & 63;
    const int l   = ln & 15;
    const int qd  = ln >> 4;                // quad

    // Q A-fragments (A[m=lane&15][k=quad*8+j]), kept in registers.
    short8 qf[2][2];
#pragma unroll
    for (int b = 0; b < 2; ++b) {
        const size_t rb = ((size_t)(b * HDIM + h) * SDIM + (s0 + wv * 16 + l)) * DDIM;
#pragma unroll
        for (int kc = 0; kc < 2; ++kc)
            qf[b][kc] = *(const short8*)(qg + rb + kc * 32 + qd * 8);
    }

    f32x4 oacc[2][4];
#pragma unroll
    for (int b = 0; b < 2; ++b)
#pragma unroll
        for (int nd = 0; nd < 4; ++nd)
            oacc[b][nd] = (f32x4){0.f, 0.f, 0.f, 0.f};

    // staging geometry: lane ln covers dest row (p*32 + wv*8 + ln>>3),
    // chunk (ln&7); source chunk is inverse-swizzled so swizzled reads match.
    const int ln8 = ln >> 3;                 // dest row within 8-row group
    const int sc_ = (ln & 7) ^ ln8;          // pre-swizzled source 16-B chunk
    const int mrow0 = s0 + wv * 16 + qd * 4; // this quad's first C row

    // stage K/V tile at t0s into LDS buffer bufi (8 async 16-B DMAs/thread)
    auto STAGE = [&](int bufi, int t0s) {
#pragma unroll
        for (int b = 0; b < 2; ++b) {
            const short* kb = kg  + ((size_t)(b * HDIM + h) * SDIM + t0s) * DDIM;
            const short* vb = vtg + ((size_t)(b * HDIM + h) * DDIM) * SDIM + t0s;
#pragma unroll
            for (int p = 0; p < 2; ++p) {
                int rr = p * 32 + wv * 8 + ln8;
                g2l16(kb + (size_t)rr * DDIM + sc_ * 8, &Ks [bufi][b][p * 2048 + wv * 512]);
                g2l16(vb + (size_t)rr * SDIM + sc_ * 8, &VTs[bufi][b][p * 2048 + wv * 512]);
            }
        }
    };

    const int tbeg = tz * (SDIM / 2);
    const int tend = tbeg + SDIM / 2;

    STAGE(0, tbeg);          // prologue: fill buffer 0
    __syncthreads();         // drain -> buffer 0 ready

    int cur = 0;
    for (int t0 = tbeg; t0 < tend; t0 += 64) {
        // issue NEXT tile's DMA first -- lands under this tile's compute.
        // (buf cur^1 holds tile t0-64, fully consumed before the last barrier)
        if (t0 + 64 < tend) STAGE(cur ^ 1, t0 + 64);

        // mask bits: one u64 per C row covers the 64 t of this tile
        unsigned long long mw[4];
#pragma unroll
        for (int rg = 0; rg < 4; ++rg)
            mw[rg] = mbits[(size_t)(mrow0 + rg) * (SDIM / 64) + (t0 >> 6)];

        // QK^T: B[k][n] = K[n][k] -> read K rows like A-frags
        f32x4 sc[2][4];
#pragma unroll
        for (int b = 0; b < 2; ++b)
#pragma unroll
            for (int nt = 0; nt < 4; ++nt) {
                f32x4 acc = (f32x4){0.f, 0.f, 0.f, 0.f};
#pragma unroll
                for (int kc = 0; kc < 2; ++kc) {
                    short8 bf = *(const short8*)ldsp(&Ks[cur][b][0], nt * 16 + l, kc * 32 + qd * 8);
                    acc = __builtin_amdgcn_mfma_f32_16x16x32_bf16(qf[b][kc], bf, acc, 0, 0, 0);
                }
                sc[b][nt] = acc;
            }

        // batch-pair softmax; P -> LDS (bf16, wave-local; same-wave DS ordering)
#pragma unroll
        for (int nt = 0; nt < 4; ++nt)
#pragma unroll
            for (int rg = 0; rg < 4; ++rg) {
                float dd = (sc[0][nt][rg] - sc[1][nt][rg]) * 0.125f;
                bool msk = (mw[rg] >> (nt * 16 + l)) & 1ull;
                float p0 = msk ? 0.5f : __builtin_amdgcn_rcpf(1.f + __expf(-dd));
                float p1 = 1.f - p0;
                int row = wv * 16 + qd * 4 + rg;
                *ldsp(&Ps[0][0], row, nt * 16 + l) = f2bf(p0);
                *ldsp(&Ps[1][0], row, nt * 16 + l) = f2bf(p1);
            }

        // PV: A from Ps (own 16-row strip), B from VTs (rows = d)
#pragma unroll
        for (int b = 0; b < 2; ++b)
#pragma unroll
            for (int kc = 0; kc < 2; ++kc) {
                short8 af = *(const short8*)ldsp(&Ps[b][0], wv * 16 + l, kc * 32 + qd * 8);
#pragma unroll
                for (int nd = 0; nd < 4; ++nd) {
                    short8 bf = *(const short8*)ldsp(&VTs[cur][b][0], nd * 16 + l, kc * 32 + qd * 8);
                    oacc[b][nd] = __builtin_amdgcn_mfma_f32_16x16x32_bf16(af, bf, oacc[b][nd], 0, 0, 0);
                }
            }

        // DENSE coalesced fp32 attn write: each store instruction covers
        // 4 full 256-B row segments (16 lanes x 16 B per row), no gaps.
        {
            int rr2 = ln >> 4;               // row within 4-row group
            int c2  = ln & 15;               // 16-B chunk within the 256-B row
#pragma unroll
            for (int b = 0; b < 2; ++b) {
                size_t ab = ((size_t)(b * HDIM + h) * SDIM + s0) * (size_t)SDIM + t0;
#pragma unroll
                for (int sub = 0; sub < 4; ++sub) {
                    int row = wv * 16 + sub * 4 + rr2;
                    bh4 pv = *(const bh4*)ldsp(&Ps[b][0], row, c2 * 4);
                    f32x4 o;
#pragma unroll
                    for (int j = 0; j < 4; ++j) o[j] = bf2f(pv[j]);
                    __builtin_nontemporal_store(
                        o, (f32x4*)(attng + ab + (size_t)row * SDIM + c2 * 4));
                }
            }
        }

        __syncthreads();   // single barrier/iter: next tile ready, prev buf free
        cur ^= 1;
    }

    // epilogue: partial O (C-layout: col=lane&15, row=quad*4+reg) -> ws
#pragma unroll
    for (int b = 0; b < 2; ++b)
#pragma unroll
        for (int nd = 0; nd < 4; ++nd)
#pragma unroll
            for (int rg = 0; rg < 4; ++rg) {
                int srow = s0 + wv * 16 + qd * 4 + rg;
                opart[(size_t)tz * OUTN +
                      ((size_t)(b * HDIM + h) * SDIM + srow) * DDIM + nd * 16 + l] =
                    oacc[b][nd][rg];
            }
}

// ---------------------------------------------------------------------------
// Sum the two t-half partials into out.
__global__ void combine(const float* __restrict__ opart, float* __restrict__ outg) {
    int gid = blockIdx.x * 256 + threadIdx.x;           // OUTN/4 threads
    f32x4 a = *(const f32x4*)(opart + (size_t)gid * 4);
    f32x4 b = *(const f32x4*)(opart + (size_t)OUTN + (size_t)gid * 4);
    *(f32x4*)(outg + (size_t)gid * 4) = a + b;
}

// ---------------------------------------------------------------------------
extern "C" void kernel_launch(void* const* d_in, const int* in_sizes, int n_in,
                              void* d_out, int out_size, void* d_ws, size_t ws_size,
                              hipStream_t stream) {
    (void)in_sizes; (void)n_in; (void)out_size; (void)ws_size;
    const float* qg  = (const float*)d_in[0];
    const float* kg  = (const float*)d_in[1];
    const float* vg  = (const float*)d_in[2];
    const int*   msk = (const int*)d_in[3];

    float* outg  = (float*)d_out;
    float* attng = outg + (size_t)OUTN;

    char* ws = (char*)d_ws;
    unsigned long long* bits = (unsigned long long*)ws;            // 2 MB
    short* qb = (short*)(ws + (size_t) 2 * 1024 * 1024);           // 4 MB
    short* kb = (short*)(ws + (size_t) 6 * 1024 * 1024);           // 4 MB
    short* vt = (short*)(ws + (size_t)10 * 1024 * 1024);           // 4 MB
    float* op = (float*)(ws + (size_t)14 * 1024 * 1024);           // 16.8 MB

    pack_mask  <<<dim3(SDIM * SDIM / 256), dim3(256), 0, stream>>>(msk, bits);
    cvt_bf16   <<<dim3(OUTN / (8 * 256)), dim3(256), 0, stream>>>(qg, qb);
    cvt_bf16   <<<dim3(OUTN / (8 * 256)), dim3(256), 0, stream>>>(kg, kb);
    transpose_v<<<dim3(OUTN / (8 * 256)), dim3(256), 0, stream>>>(vg, vt);
    attn_fused <<<dim3(SDIM / 64, HDIM, 2), dim3(256), 0, stream>>>(qb, kb, vt, bits, attng, op);
    combine    <<<dim3(OUTN / (4 * 256)), dim3(256), 0, stream>>>(op, outg);
}